// Round 9
// baseline (47.638 us; speedup 1.0000x reference)
//
#include <hip/hip_runtime.h>

// Problem constants (match reference setup_inputs)
#define K_SIZE 5
#define PAD 2
#define SAMPLE_NUM 15
#define DEPTH_MAX 192.0f

constexpr int B = 2, C = 32, H = 240, W = 320;
constexpr int HW  = H * W;
constexpr int BHW = B * HW;                 // 153600
constexpr int TOT = B * C * HW;             // 4915200 (features element count)
constexpr size_t WS_NEED = (size_t)SAMPLE_NUM * BHW * sizeof(float);  // 9.2 MB

typedef float float4a __attribute__((ext_vector_type(4), aligned(16)));
typedef float float4u __attribute__((ext_vector_type(4), aligned(4)));  // 4B-aligned ok

// ---------------- Kernel A: pre-weights + softmax, thread = (pixel, sample-slot) ----
// Branch-free: unconditional clamped loads, validity folded in via selects.
// ws layout: wpost[s][BHW] -> gather loads weights as aligned float4 across pixels.
// Stored value = final accumulation weight (softmax prob; 0 for OOB zero-pad samples).
__global__ __launch_bounds__(256) void weights_kernel(
    const float* __restrict__ depth,      // [B,1,H,W]
    const float* __restrict__ sn,         // [B,3,H,W]
    const float* __restrict__ guide,      // [B,H,W,25]
    const int*   __restrict__ sample_idx, // [15]
    float* __restrict__ wpost)            // [15][BHW]
{
    const int t   = threadIdx.x;
    const int s   = t & 15;               // sample slot (15 = pad lane)
    const int lp  = t >> 4;               // local pixel
    const int pg  = blockIdx.x * 16 + lp; // global pixel id
    const int b   = pg / HW;
    const int pix = pg - b * HW;
    const int y   = pix / W;
    const int x   = pix - y * W;

    const float* snb = sn + (size_t)b * 3 * HW;
    const float* db  = depth + (size_t)b * HW;

    const int pp = sample_idx[(s < SAMPLE_NUM) ? s : 0];  // pad lane: harmless dup
    const int dy = pp / K_SIZE - PAD;
    const int dx = pp - (pp / K_SIZE) * K_SIZE - PAD;
    const int yy = y + dy, xx = x + dx;
    const bool inb = (s < SAMPLE_NUM) && (yy >= 0) && (yy < H) && (xx >= 0) && (xx < W);
    const int  noff = min(max(yy, 0), H - 1) * W + min(max(xx, 0), W - 1);  // clamped

    // unconditional loads (finite data; result masked below)
    const float d  = db[noff];
    const int   o  = pix * 3;  // center_n = RAW RESHAPE [B,3,H,W]->(B,H,W,3): 3 contiguous floats
    const float cn0 = snb[o], cn1 = snb[o + 1], cn2 = snb[o + 2];
    const float d0 = snb[noff]          - cn0;
    const float d1 = snb[HW + noff]     - cn1;
    const float d2 = snb[2 * HW + noff] - cn2;
    const float gv = guide[((size_t)b * HW + pix) * 25 + pp];

    const float diff = sqrtf(d0 * d0 + d1 * d1 + d2 * d2);
    const bool  ok   = inb && (d > 0.0f) && (d < DEPTH_MAX);
    const float prew = ok ? __expf(-0.5f * diff) * gv : 0.0f;  // pre-softmax weight

    // softmax across the 16-lane group (pad lane prew=0: can't raise max since all >=0;
    // its exp term is excluded from the sum)
    float m = prew;
    #pragma unroll
    for (int mask = 1; mask < 16; mask <<= 1)
        m = fmaxf(m, __shfl_xor(m, mask, 16));
    float e = (s < SAMPLE_NUM) ? __expf(prew - m) : 0.0f;
    float sum = e;
    #pragma unroll
    for (int mask = 1; mask < 16; mask <<= 1)
        sum += __shfl_xor(sum, mask, 16);

    if (s < SAMPLE_NUM)
        wpost[(size_t)s * BHW + pg] = inb ? (e / sum) : 0.0f;  // OOB -> 0 (zero-pad feature)
}

// ---------------- Kernel B: branch-free vector gather, thread = (quad, channel) -----
// 4800 blocks = 600 pixel-chunks x 8 channel-groups; block = 64 quads x 4 channel-slots.
// OOB handling: weights are exactly 0 at OOB -> load UNCLAMPED flat index (reads spill
// into adjacent rows/planes: finite junk x 0 = 0). Only reads displaced by the global
// buffer clamp need an exact fixup:
//   underflow: fbase==0      && yy==0  reachable from y<=2   && x0==0     && dx<0
//   overflow:  fbase==last   && yy==H-1 reachable from y>=H-3 && x0==W-4  && dx>0
constexpr int CHUNKS = BHW / 256;       // 600
constexpr int XCHUNK = CHUNKS / 8;      // 75 contiguous chunks per XCD

__global__ __launch_bounds__(256, 6) void gather_kernel(
    const float* __restrict__ features,   // [B,C,H,W]
    const int*   __restrict__ sample_idx, // [15]
    const float* __restrict__ wpost,      // [15][BHW]
    float* __restrict__ out,              // [B,C,H,W]
    float* __restrict__ feat_out)         // [B,C,H,W]
{
    const int bid   = blockIdx.x;         // 0..4799
    const int xcd   = bid & 7;
    const int r     = bid >> 3;           // 0..599
    const int cg    = r / XCHUNK;         // channel group 0..7
    const int chunk = xcd * XCHUNK + (r - (r / XCHUNK) * XCHUNK);  // 0..599

    const int t     = threadIdx.x;
    const int q     = t & 63;             // quad within chunk (wave = 64 quads, 1 channel)
    const int cslot = t >> 6;             // 0..3 (wave-uniform channel)
    const int c     = cg * 4 + cslot;

    const int p0   = chunk * 256 + q * 4; // global pixel id of quad start
    const int b    = p0 / HW;             // uniform per block (256 | HW)
    const int pix0 = p0 - b * HW;
    const int y    = pix0 / W;
    const int x0   = pix0 - y * W;        // quads never cross rows (4 | W)

    const int fbase = (b * C + c) * HW;   // flat feature-plane base (fits int)

    float4a acc = {0.0f, 0.0f, 0.0f, 0.0f};
    #pragma unroll
    for (int s = 0; s < SAMPLE_NUM; ++s) {
        int pp = sample_idx[s];           // wave-uniform -> scalar
        int dy = pp / K_SIZE - PAD;
        int dx = pp - (pp / K_SIZE) * K_SIZE - PAD;
        int yy = min(max(y + dy, 0), H - 1);             // OOB rows: w4 = 0
        int flat = fbase + yy * W + x0 + dx;             // UNCLAMPED x (w-masked)
        flat = min(max(flat, 0), TOT - 4);               // only global extremes clamp
        float4a w4 = *(const float4a*)(wpost + (size_t)s * BHW + p0);  // aligned
        float4u f4 = *(const float4u*)(features + flat); // 4B-aligned dwordx4
        acc += w4 * f4;
    }

    // exact fixup wherever the flat clamp could have displaced a nonzero-weight read
    const bool fix = (fbase == 0 && x0 == 0 && y <= 2) ||
                     (fbase == (B * C - 1) * HW && x0 == W - 4 && y >= H - 3);
    if (fix) {
        const float* fb = features + fbase;
        float a0 = 0, a1 = 0, a2 = 0, a3 = 0;
        #pragma unroll
        for (int s = 0; s < SAMPLE_NUM; ++s) {
            int pp = sample_idx[s];
            int dy = pp / K_SIZE - PAD;
            int dx = pp - (pp / K_SIZE) * K_SIZE - PAD;
            int yy = min(max(y + dy, 0), H - 1);
            const float* frow = fb + yy * W;
            const float* wrow = wpost + (size_t)s * BHW + p0;
            int xb = x0 + dx;
            a0 += wrow[0] * frow[min(max(xb + 0, 0), W - 1)];
            a1 += wrow[1] * frow[min(max(xb + 1, 0), W - 1)];
            a2 += wrow[2] * frow[min(max(xb + 2, 0), W - 1)];
            a3 += wrow[3] * frow[min(max(xb + 3, 0), W - 1)];
        }
        acc = float4a{a0, a1, a2, a3};
    }

    const size_t ob = (size_t)fbase + pix0;
    float4a pf = *(const float4a*)(features + fbase + pix0);  // aligned passthrough
    *(float4a*)(out + ob)      = acc;
    *(float4a*)(feat_out + ob) = pf;
}

// ---------------- Fallback (round-3 style fused kernel) if ws is too small ----------
__global__ __launch_bounds__(256) void fused_fallback(
    const float* __restrict__ depth, const float* __restrict__ sn,
    const float* __restrict__ features, const float* __restrict__ guide,
    const int* __restrict__ sample_idx, float* __restrict__ out,
    float* __restrict__ feat_out)
{
    constexpr int PIX_BLOCKS = BHW / 256;
    int pb = blockIdx.x % PIX_BLOCKS;
    int g  = blockIdx.x / PIX_BLOCKS;
    int n  = pb * 256 + threadIdx.x;
    int b = n / HW, pix = n - b * HW, y = pix / W, x = pix - y * W;
    const float* snb = sn + (size_t)b * 3 * HW;
    const float* db  = depth + (size_t)b * HW;
    const float* gb  = guide + ((size_t)b * HW + pix) * 25;
    int o = pix * 3;
    float cn0 = snb[o], cn1 = snb[o + 1], cn2 = snb[o + 2];
    float w[SAMPLE_NUM]; int offs[SAMPLE_NUM]; bool inbv[SAMPLE_NUM];
    float m = 0.0f;
    #pragma unroll
    for (int s = 0; s < SAMPLE_NUM; ++s) {
        int pp = sample_idx[s];
        int dy = pp / K_SIZE - PAD, dx = pp - (pp / K_SIZE) * K_SIZE - PAD;
        int yy = y + dy, xx = x + dx;
        bool inb = (yy >= 0) && (yy < H) && (xx >= 0) && (xx < W);
        inbv[s] = inb;
        int noff = inb ? (yy * W + xx) : pix;
        offs[s] = noff;
        float ww = 0.0f;
        if (inb) {
            float d = db[noff];
            if (d > 0.0f && d < DEPTH_MAX) {
                float d0 = snb[noff] - cn0, d1 = snb[HW + noff] - cn1, d2 = snb[2 * HW + noff] - cn2;
                ww = __expf(-0.5f * sqrtf(d0 * d0 + d1 * d1 + d2 * d2)) * gb[pp];
            }
        }
        w[s] = ww; m = fmaxf(m, ww);
    }
    float sum = 0.0f;
    #pragma unroll
    for (int s = 0; s < SAMPLE_NUM; ++s) { w[s] = __expf(w[s] - m); sum += w[s]; }
    float inv = 1.0f / sum;
    #pragma unroll
    for (int s = 0; s < SAMPLE_NUM; ++s) w[s] = inbv[s] ? (w[s] * inv) : 0.0f;
    const float* fb = features + (size_t)b * C * HW;
    float* ob = out + (size_t)b * C * HW;
    float* fob = feat_out + (size_t)b * C * HW;
    int c0 = g * 8;
    #pragma unroll
    for (int cc = 0; cc < 8; ++cc) {
        const float* fc = fb + (c0 + cc) * HW;
        float acc = 0.0f;
        #pragma unroll
        for (int s = 0; s < SAMPLE_NUM; ++s) acc += w[s] * fc[offs[s]];
        ob[(size_t)(c0 + cc) * HW + pix] = acc;
        fob[(size_t)(c0 + cc) * HW + pix] = fc[pix];
    }
}

extern "C" void kernel_launch(void* const* d_in, const int* in_sizes, int n_in,
                              void* d_out, int out_size, void* d_ws, size_t ws_size,
                              hipStream_t stream) {
    const float* depth      = (const float*)d_in[0];
    const float* sn         = (const float*)d_in[1];
    const float* features   = (const float*)d_in[2];
    const float* guide      = (const float*)d_in[3];
    const int*   sample_idx = (const int*)d_in[4];

    float* out      = (float*)d_out;                      // [B,C,H,W]
    float* feat_out = (float*)d_out + (size_t)B * C * HW; // [B,C,H,W]

    if (ws_size >= WS_NEED) {
        float* wpost = (float*)d_ws;
        weights_kernel<<<BHW / 16, 256, 0, stream>>>(depth, sn, guide, sample_idx, wpost);
        gather_kernel<<<CHUNKS * 8, 256, 0, stream>>>(features, sample_idx, wpost, out, feat_out);
    } else {
        fused_fallback<<<(BHW / 256) * 4, 256, 0, stream>>>(
            depth, sn, features, guide, sample_idx, out, feat_out);
    }
}